// Round 12
// baseline (182.093 us; speedup 1.0000x reference)
//
#include <hip/hip_runtime.h>

// Problem constants
#define NB      32      // batch
#define INF     128     // in_flt
#define NPIX    64      // N
#define TSP     16      // t
#define OUTF    32      // out_flt
#define FF      16      // intermediate features
#define D_IN    768     // 3*t*t
#define D_OUT   8192    // out_flt*t*t
#define NCOL    (D_OUT*FF)   // 131072
#define OUTCH   160     // in_flt + out_flt
#define BSTRIDE 655360  // 160*64*64 floats per batch in d_out
#define KCH     4       // k-chunks
#define KROWS   192     // rows per k-chunk
#define NBNCOL  ((size_t)NB*NCOL)

// K1: fused strided conv (128ch,4x4,stride4 -> 3ch) + x->out concat copy.
// A written k-major: At[k*32 + b].
__global__ __launch_bounds__(256) void k1_conv_copy(
    const float* __restrict__ x, const float* __restrict__ wc,
    float* __restrict__ out, float* __restrict__ At)
{
    __shared__ float sW[3*128*16];     // w_conv, 24 KB
    __shared__ float sP[16][16][3];    // partials [icg][j][c3]
    const int b   = blockIdx.x >> 4;
    const int oi  = blockIdx.x & 15;
    const int tid = threadIdx.x;
    for (int idx = tid; idx < 6144; idx += 256) sW[idx] = wc[idx];
    __syncthreads();
    const int icg = tid >> 4;          // 0..15 -> ic block of 8
    const int j   = tid & 15;          // output col
    float a0 = 0.f, a1 = 0.f, a2 = 0.f;
    for (int ic8 = 0; ic8 < 8; ++ic8) {
        const int ic = icg*8 + ic8;
        #pragma unroll
        for (int ki = 0; ki < 4; ++ki) {
            const int row = 4*oi + ki;
            const float4 xv = *(const float4*)(x + ((size_t)(b*INF+ic)*NPIX + row)*NPIX + 4*j);
            *(float4*)(out + ((size_t)(b*OUTCH+ic)*NPIX + row)*NPIX + 4*j) = xv;
            const float* w0 = sW + ((0*INF+ic)*4 + ki)*4;
            const float* w1 = sW + ((1*INF+ic)*4 + ki)*4;
            const float* w2 = sW + ((2*INF+ic)*4 + ki)*4;
            a0 += xv.x*w0[0] + xv.y*w0[1] + xv.z*w0[2] + xv.w*w0[3];
            a1 += xv.x*w1[0] + xv.y*w1[1] + xv.z*w1[2] + xv.w*w1[3];
            a2 += xv.x*w2[0] + xv.y*w2[1] + xv.z*w2[2] + xv.w*w2[3];
        }
    }
    sP[icg][j][0] = a0; sP[icg][j][1] = a1; sP[icg][j][2] = a2;
    __syncthreads();
    if (tid < 48) {
        const int c3 = tid >> 4, jj = tid & 15;
        float s = 0.f;
        #pragma unroll
        for (int g = 0; g < 16; ++g) s += sP[g][jj][c3];
        const int k = c3*256 + oi*16 + jj;    // reshape(3,16,16) C-order
        At[k*32 + b] = s;
    }
}

// K2 v12: CONTIGUOUS T-streaming. R10's diag_stream read the same 402 MB
// LINEARLY at 6.4 TB/s (63 us) while k2 takes 145 us with "warm == cold"
// timing -> bound is ACCESS ORDER (k-major 512KB-stride = 1 new page /
// same-channel hit per wave-instruction; translation/channel pipe
// serializes), not bytes/instructions/occupancy. v12 walks T exactly like
// diag_stream: block = (kc, cc) covers rows [kc*192,kc*192+192) x 1024
// cols; per row the block reads 4 KB CONTIGUOUS (1 float4/thread, 4
// wave-instrs per page, rows sequential). A-slice (24 KB) in LDS
// (broadcast ds_read, lgkmcnt); depth-4 named T-ring on pure vmcnt;
// acc[32][4]/thread. Each block writes k-partials Mp[kc]; K3 merges.
__global__ __launch_bounds__(256, 2) void k2_gemm(
    const float* __restrict__ At, const float* __restrict__ Tm,
    float* __restrict__ Mp)
{
    __shared__ float sA[KROWS*32];     // 24 KB
    const int tid = threadIdx.x;
    const int kc  = blockIdx.x >> 7;   // 0..3
    const int cc  = blockIdx.x & 127;  // 0..127
    const int k0g = kc * KROWS;
    {   // stage this k-chunk's A rows (6144 floats, float4-coalesced)
        const float4* src = (const float4*)(At + k0g*32);
        float4* dst = (float4*)sA;
        #pragma unroll
        for (int i = 0; i < 6; ++i) dst[tid + i*256] = src[tid + i*256];
    }
    __syncthreads();

    float acc[32][4];
    #pragma unroll
    for (int i = 0; i < 32; ++i)
        #pragma unroll
        for (int j = 0; j < 4; ++j) acc[i][j] = 0.f;

    const float* tp = Tm + (size_t)k0g*NCOL + cc*1024 + tid*4;

#define TLD(KK) (*(const float4*)(tp + (size_t)(KK)*NCOL))
#define FMG(G, AV, T4) { \
  acc[(G)*4+0][0]+=AV.x*T4.x; acc[(G)*4+0][1]+=AV.x*T4.y; acc[(G)*4+0][2]+=AV.x*T4.z; acc[(G)*4+0][3]+=AV.x*T4.w; \
  acc[(G)*4+1][0]+=AV.y*T4.x; acc[(G)*4+1][1]+=AV.y*T4.y; acc[(G)*4+1][2]+=AV.y*T4.z; acc[(G)*4+1][3]+=AV.y*T4.w; \
  acc[(G)*4+2][0]+=AV.z*T4.x; acc[(G)*4+2][1]+=AV.z*T4.y; acc[(G)*4+2][2]+=AV.z*T4.z; acc[(G)*4+2][3]+=AV.z*T4.w; \
  acc[(G)*4+3][0]+=AV.w*T4.x; acc[(G)*4+3][1]+=AV.w*T4.y; acc[(G)*4+3][2]+=AV.w*T4.z; acc[(G)*4+3][3]+=AV.w*T4.w; }
#define ALD(J) \
    const float* ar = sA + (k0+(J))*32; \
    const float4 a0 = *(const float4*)(ar +  0); \
    const float4 a1 = *(const float4*)(ar +  4); \
    const float4 a2 = *(const float4*)(ar +  8); \
    const float4 a3 = *(const float4*)(ar + 12); \
    const float4 a4 = *(const float4*)(ar + 16); \
    const float4 a5 = *(const float4*)(ar + 20); \
    const float4 a6 = *(const float4*)(ar + 24); \
    const float4 a7 = *(const float4*)(ar + 28);
#define STEP(J, RT) { ALD(J) \
    FMG(0,a0,RT) FMG(1,a1,RT) FMG(2,a2,RT) FMG(3,a3,RT) \
    FMG(4,a4,RT) FMG(5,a5,RT) FMG(6,a6,RT) FMG(7,a7,RT) \
    RT = TLD(k0 + 4 + (J)); }
#define STEPE(J, RT) { ALD(J) \
    FMG(0,a0,RT) FMG(1,a1,RT) FMG(2,a2,RT) FMG(3,a3,RT) \
    FMG(4,a4,RT) FMG(5,a5,RT) FMG(6,a6,RT) FMG(7,a7,RT) }

    float4 r0=TLD(0), r1=TLD(1), r2=TLD(2), r3=TLD(3);   // depth-4 row ring

    int k0 = 0;
    for (; k0 < KROWS - 4; k0 += 4) {
        STEP(0, r0) STEP(1, r1) STEP(2, r2) STEP(3, r3)
    }
    // epilogue: k0 == KROWS-4, consume only
    STEPE(0, r0) STEPE(1, r1) STEPE(2, r2) STEPE(3, r3)
#undef STEPE
#undef STEP
#undef ALD
#undef FMG
#undef TLD

    float* mp = Mp + (size_t)kc*NBNCOL + cc*1024 + tid*4;
    #pragma unroll
    for (int bb = 0; bb < 32; ++bb)
        *(float4*)(mp + (size_t)bb*NCOL) =
            make_float4(acc[bb][0], acc[bb][1], acc[bb][2], acc[bb][3]);
}

// K3: out[j,d] = sum_i exp(-sum_f |M[i,d,f]-M[j,d,f]|) - 1.
// Sums the 4 k-chunk partials while loading into LDS.
__global__ __launch_bounds__(256) void k3_pairs(
    const float* __restrict__ Mp, float* __restrict__ outS)
{
    extern __shared__ float sM[];      // 32*32*17 floats
    const int tid = threadIdx.x;
    const int dd0 = blockIdx.x * 32;
    for (int idx = tid; idx < 32*32*16; idx += 256) {
        const int i = idx >> 9, rem = idx & 511, d = rem >> 4, f = rem & 15;
        const size_t off = (size_t)i*NCOL + (size_t)dd0*16 + rem;
        sM[(i*32 + d)*17 + f] = (Mp[off] + Mp[off + NBNCOL])
                              + (Mp[off + 2*NBNCOL] + Mp[off + 3*NBNCOL]);
    }
    __syncthreads();
    const int j = tid >> 3;
    for (int q = 0; q < 4; ++q) {
        const int d = (tid & 7) + q*8;
        float mj[16];
        const float* pj = sM + (j*32 + d)*17;
        #pragma unroll
        for (int f = 0; f < 16; ++f) mj[f] = pj[f];
        float acc = 0.f;
        for (int i = 0; i < 32; ++i) {
            const float* pi = sM + (i*32 + d)*17;
            float dist = 0.f;
            #pragma unroll
            for (int f = 0; f < 16; ++f) dist += fabsf(pi[f] - mj[f]);
            acc += __expf(-dist);
        }
        outS[(size_t)j*D_OUT + dd0 + d] = acc - 1.0f;
    }
}

// K4: ConvTranspose2d, stride==kernel -> no overlap.
__global__ __launch_bounds__(256) void k4_deconv(
    const float* __restrict__ outS, const float* __restrict__ wd,
    float* __restrict__ out)
{
    __shared__ float sO[32*256];       // [ic][si*16+sj]
    __shared__ float sWd[32*16];       // [ic][ki*4+kj]
    const int b   = blockIdx.x >> 5;
    const int oc  = blockIdx.x & 31;
    const int tid = threadIdx.x;
    for (int idx = tid; idx < 8192; idx += 256) sO[idx] = outS[(size_t)b*D_OUT + idx];
    for (int idx = tid; idx < 512; idx += 256) {
        const int ic = idx >> 4, r = idx & 15;
        sWd[idx] = wd[((ic*32 + oc) << 4) + r];   // IOHW: (ic, oc, ki, kj)
    }
    __syncthreads();
    float* ob = out + (size_t)b*BSTRIDE + (size_t)(128 + oc)*4096;
    for (int s = 0; s < 16; ++s) {
        const int p  = tid + (s << 8);
        const int i  = p >> 6, jc = p & 63;
        const int si = i >> 2, ki = i & 3, sj = jc >> 2, kj = jc & 3;
        float acc = 0.f;
        #pragma unroll
        for (int ic = 0; ic < 32; ++ic)
            acc += sO[ic*256 + si*16 + sj] * sWd[ic*16 + ki*4 + kj];
        ob[p] = acc;
    }
}

extern "C" void kernel_launch(void* const* d_in, const int* in_sizes, int n_in,
                              void* d_out, int out_size, void* d_ws, size_t ws_size,
                              hipStream_t stream) {
    const float* x  = (const float*)d_in[0];
    const float* wc = (const float*)d_in[1];
    const float* Tm = (const float*)d_in[2];
    const float* wd = (const float*)d_in[3];
    float* out  = (float*)d_out;
    float* At   = (float*)d_ws;                        // 96 KB @ 0
    float* Mp   = (float*)((char*)d_ws + (1 << 20));   // 67 MB @ 1 MB
    float* outS = (float*)((char*)d_ws + (72 << 20));  // 1 MB @ 72 MB

    k1_conv_copy<<<NB*TSP, 256, 0, stream>>>(x, wc, out, At);                   // 512 blocks
    k2_gemm    <<<KCH*128, 256, 0, stream>>>(At, Tm, Mp);                       // 512 blocks
    k3_pairs   <<<D_OUT/32, 256, 32*32*17*sizeof(float), stream>>>(Mp, outS);   // 256 blocks
    k4_deconv  <<<NB*OUTF, 256, 0, stream>>>(outS, wd, out);                    // 1024 blocks
}